// Round 1
// baseline (128.392 us; speedup 1.0000x reference)
//
#include <hip/hip_runtime.h>

#define CONF_THRES 0.25f

// Grid-stride reduction: each thread accumulates masked per-detection values,
// wave-level shuffle reduce (64 lanes), lane 0 atomicAdd to the scalar output.
__global__ void yolo_target_reduce(const float* __restrict__ post,   // [N,6]
                                   const float* __restrict__ boxes,  // [N,4]
                                   float* __restrict__ out, int n) {
    int tid = blockIdx.x * blockDim.x + threadIdx.x;
    int stride = gridDim.x * blockDim.x;

    float acc = 0.0f;
    for (int i = tid; i < n; i += stride) {
        // post row i: need cols 4,5 -> float2 at element offset 6i+4 (8B aligned)
        float2 cs = *reinterpret_cast<const float2*>(post + 6ll * i + 4);
        // boxes row i: 4 floats, 16B aligned
        float4 b = *reinterpret_cast<const float4*>(boxes + 4ll * i);
        float per_det = cs.y + (b.x + b.y) + (b.z + b.w);
        acc += (cs.x >= CONF_THRES) ? per_det : 0.0f;
    }

    // wave64 butterfly reduction
    #pragma unroll
    for (int off = 32; off > 0; off >>= 1)
        acc += __shfl_down(acc, off, 64);

    if ((threadIdx.x & 63) == 0)
        atomicAdd(out, acc);
}

extern "C" void kernel_launch(void* const* d_in, const int* in_sizes, int n_in,
                              void* d_out, int out_size, void* d_ws, size_t ws_size,
                              hipStream_t stream) {
    const float* post  = (const float*)d_in[0];   // [N,6] f32
    const float* boxes = (const float*)d_in[1];   // [N,4] f32
    float* out = (float*)d_out;                   // scalar f32

    int n = in_sizes[0] / 6;                      // N = 4,000,000

    // d_out is poisoned once (0xAA) and NOT re-poisoned between replays:
    // zero it ourselves every call (async memset is graph-capture safe).
    hipMemsetAsync(out, 0, sizeof(float), stream);

    const int block = 256;
    int max_blocks = 2048;                        // 256 CU * 8 blocks/CU
    int blocks = (n + block - 1) / block;
    if (blocks > max_blocks) blocks = max_blocks;

    yolo_target_reduce<<<blocks, block, 0, stream>>>(post, boxes, out, n);
}

// Round 2
// 32.192 us; speedup vs baseline: 3.9883x; 3.9883x over previous
//
#include <hip/hip_runtime.h>

#define CONF_THRES 0.25f

__device__ __forceinline__ float row_val(const float* __restrict__ post,
                                         const float* __restrict__ boxes, int i) {
    // post row i: cols 4,5 -> float2 at element 6i+4 (8B aligned)
    float2 cs = *reinterpret_cast<const float2*>(post + 6ll * i + 4);
    // boxes row i: float4, 16B aligned
    float4 b = *reinterpret_cast<const float4*>(boxes + 4ll * i);
    float per = cs.y + (b.x + b.y) + (b.z + b.w);
    return (cs.x >= CONF_THRES) ? per : 0.0f;
}

// Stage 1: grid-stride with 4-way unroll (8 independent loads in flight),
// block reduction via wave shuffle + LDS, ONE plain store per block. No atomics.
__global__ void __launch_bounds__(256) yolo_partial(const float* __restrict__ post,
                                                    const float* __restrict__ boxes,
                                                    float* __restrict__ partials, int n) {
    int tid = blockIdx.x * blockDim.x + threadIdx.x;
    int stride = gridDim.x * blockDim.x;

    float acc = 0.0f;
    int i = tid;
    for (; i + 3 * stride < n; i += 4 * stride) {
        float a0 = row_val(post, boxes, i);
        float a1 = row_val(post, boxes, i + stride);
        float a2 = row_val(post, boxes, i + 2 * stride);
        float a3 = row_val(post, boxes, i + 3 * stride);
        acc += (a0 + a1) + (a2 + a3);
    }
    for (; i < n; i += stride)
        acc += row_val(post, boxes, i);

    // wave64 reduction
    #pragma unroll
    for (int off = 32; off > 0; off >>= 1)
        acc += __shfl_down(acc, off, 64);

    __shared__ float ws[4];
    int wid = threadIdx.x >> 6;
    if ((threadIdx.x & 63) == 0) ws[wid] = acc;
    __syncthreads();
    if (threadIdx.x == 0)
        partials[blockIdx.x] = (ws[0] + ws[1]) + (ws[2] + ws[3]);
}

// Stage 2: one block sums the per-block partials and writes the scalar.
__global__ void __launch_bounds__(256) yolo_final(const float* __restrict__ partials,
                                                  float* __restrict__ out, int m) {
    float acc = 0.0f;
    for (int i = threadIdx.x; i < m; i += blockDim.x)
        acc += partials[i];

    #pragma unroll
    for (int off = 32; off > 0; off >>= 1)
        acc += __shfl_down(acc, off, 64);

    __shared__ float ws[4];
    int wid = threadIdx.x >> 6;
    if ((threadIdx.x & 63) == 0) ws[wid] = acc;
    __syncthreads();
    if (threadIdx.x == 0)
        out[0] = (ws[0] + ws[1]) + (ws[2] + ws[3]);
}

extern "C" void kernel_launch(void* const* d_in, const int* in_sizes, int n_in,
                              void* d_out, int out_size, void* d_ws, size_t ws_size,
                              hipStream_t stream) {
    const float* post  = (const float*)d_in[0];   // [N,6] f32
    const float* boxes = (const float*)d_in[1];   // [N,4] f32
    float* out = (float*)d_out;                   // scalar f32
    float* partials = (float*)d_ws;               // 2048 floats of scratch

    int n = in_sizes[0] / 6;                      // N = 4,000,000

    const int block = 256;
    int blocks = 2048;                            // 8 blocks/CU on 256 CUs
    int needed = (n + block - 1) / block;
    if (blocks > needed) blocks = needed;

    yolo_partial<<<blocks, block, 0, stream>>>(post, boxes, partials, n);
    yolo_final<<<1, block, 0, stream>>>(partials, out, blocks);
}